// Round 10
// baseline (72152.875 us; speedup 1.0000x reference)
//
#include <hip/hip_runtime.h>

#define BB 32
#define TT 2048
#define HH 256
#define NT 512

typedef unsigned long long ull;
typedef unsigned int uint;

__device__ __forceinline__ float sigm(float v) { return 1.0f / (1.0f + __expf(-v)); }

__device__ __forceinline__ int aload(const int* p) {
  return __hip_atomic_load(p, __ATOMIC_RELAXED, __HIP_MEMORY_SCOPE_AGENT);
}
__device__ __forceinline__ void astore(int* p, int v) {
  __hip_atomic_store(p, v, __ATOMIC_RELAXED, __HIP_MEMORY_SCOPE_AGENT);
}
__device__ __forceinline__ ull aload64(const ull* p) {
  return __hip_atomic_load(p, __ATOMIC_RELAXED, __HIP_MEMORY_SCOPE_AGENT);
}
__device__ __forceinline__ void astore64(ull* p, ull v) {
  __hip_atomic_store(p, v, __ATOMIC_RELAXED, __HIP_MEMORY_SCOPE_AGENT);
}

// Communities: c = layer*4 + grp (8 total, XCD-aligned via c = bid&7), 16 WGs each.
// ws: markers m[8][16] ints at +0; rings at +4096: per community 2 slots x 2048 pairs
//     {tag(lo32), hbits(hi32)}, pair idx = bl*256 + col. 32 KB/community (round-8 exact).
// Thread mapping: ks = tid&15 (K-slice, interleaved k = c*64+ks*4), blg = (tid>>4)&1
// (batch half), unit = tid>>5 (one hidden col). Tile: 4 gates x 4 batches, weights
// stationary in 128 VGPRs. ks-partials reduced by in-wave shfl_xor butterfly.
__global__ __launch_bounds__(NT, 2) void lstm_scan(
    const float* __restrict__ x,     // [B,T,H]
    const float* __restrict__ W,     // [L,4,H,2H]
    const float* __restrict__ bias,  // [L,4,H]
    float* __restrict__ out,         // [B,T,H] + hT[B,H] + cT[B,H]
    ull* __restrict__ ring,
    int* __restrict__ sync)
{
    const int bid   = blockIdx.x;
    const int c     = bid & 7;        // community == XCD slot
    const int ug    = bid >> 3;       // unit group 0..15
    const int layer = c >> 2;
    const int grp   = c & 3;          // batch group
    const int tid   = threadIdx.x;
    const int ks    = tid & 15;       // K-slice lane (wave bits 0-3)
    const int blg   = (tid >> 4) & 1; // batch half
    const int unit  = tid >> 5;       // 0..15
    const int col   = ug * 16 + unit;
    const int blp   = blg * 4;        // local batch base

    int* mOwn = sync + c * 16;
    int* mSib = sync + (4 + grp) * 16;             // layer-1 community, same grp
    ull* ringOwn = ring + (size_t)c * 4096;
    ull* ringIn  = ring + (size_t)grp * 4096;      // layer-0 community, same grp

    __shared__ float inp[8][268];
    __shared__ float hrec[8][268];

    // weight-stationary registers: wreg[gate][chunk] = W[l][gate][col][c*64 + ks*4 .. +3]
    float4 wreg[4][8];
    #pragma unroll
    for (int g = 0; g < 4; ++g)
        #pragma unroll
        for (int cc = 0; cc < 8; ++cc)
            wreg[g][cc] = *(const float4*)(
                W + (((size_t)layer * 4 + g) * HH + col) * (2 * HH) + cc * 64 + ks * 4);

    float b4[4];
    #pragma unroll
    for (int g = 0; g < 4; ++g) b4[g] = bias[((size_t)layer * 4 + g) * HH + col];

    const int prow = tid >> 6;          // staging row (local batch), round-8 map
    const int pcol = (tid & 63) << 2;   // staging col base

    float c_state = 0.f;  // valid on ks<4 lanes: (bl = blp+ks, col)

    for (int t = 0; t < TT; ++t) {
        // ---- (1) input stage: x (layer0) or h0 ring poll (layer1) ----
        if (layer == 0) {
            *(float4*)&inp[prow][pcol] =
                *(const float4*)(x + ((size_t)(grp * 8 + prow) * TT + t) * HH + pcol);
        } else {
            const ull* rin = ringIn + (t & 1) * 2048 + 4 * tid;  // h0(t), tag t+1
            const uint want = (uint)(t + 1);
            uint pend = 0xFu; ull v[4];
            for (;;) {
                #pragma unroll
                for (int j = 0; j < 4; ++j)
                    if (pend & (1u << j)) v[j] = aload64(&rin[j]);
                #pragma unroll
                for (int j = 0; j < 4; ++j)
                    if ((pend & (1u << j)) && (uint)v[j] == want) {
                        inp[prow][pcol + j] = __uint_as_float((uint)(v[j] >> 32));
                        pend &= ~(1u << j);
                    }
                if (!pend) break;
                __builtin_amdgcn_s_sleep(1);
            }
        }
        __syncthreads();  // inp ready

        // ---- (2) recurrent poll -> hrec (4 pairs/thread, round-8 exact) ----
        {
            const ull* rr_ = ringOwn + ((t + 1) & 1) * 2048 + 4 * tid;  // h_l(t-1), tag t
            const uint want = (uint)t;
            uint pend = 0xFu; ull v[4];
            for (;;) {
                #pragma unroll
                for (int j = 0; j < 4; ++j)
                    if (pend & (1u << j)) v[j] = aload64(&rr_[j]);
                #pragma unroll
                for (int j = 0; j < 4; ++j)
                    if ((pend & (1u << j)) && (uint)v[j] == want) {
                        hrec[prow][pcol + j] = __uint_as_float((uint)(v[j] >> 32));
                        pend &= ~(1u << j);
                    }
                if (!pend) break;
                __builtin_amdgcn_s_sleep(1);
            }
        }
        // ---- (3) WAR gates (round-8 exact; overlaps stragglers) ----
        if (tid < 16)                    { while (aload(&mOwn[tid]) < t)          __builtin_amdgcn_s_sleep(1); }
        else if (layer == 0 && tid < 32) { while (aload(&mSib[tid - 16]) < t - 1) __builtin_amdgcn_s_sleep(1); }
        __syncthreads();  // hrec ready + gates passed
        if (tid == 0) astore(&mOwn[ug], t + 1);  // staged step t (inp + hrec consumed)

        // ---- (4) dot: weights in regs, 4 a-reads feed 64 FMA per chunk ----
        float acc[4][4];
        #pragma unroll
        for (int g = 0; g < 4; ++g)
            #pragma unroll
            for (int i = 0; i < 4; ++i) acc[g][i] = 0.f;

        #pragma unroll
        for (int cc = 0; cc < 8; ++cc) {
            const int kof = cc * 64 + ks * 4;
            #pragma unroll
            for (int i = 0; i < 4; ++i) {
                float4 a = (cc < 4) ? *(const float4*)&inp[blp + i][kof]
                                    : *(const float4*)&hrec[blp + i][kof - 256];
                #pragma unroll
                for (int g = 0; g < 4; ++g) {
                    acc[g][i] += a.x * wreg[g][cc].x + a.y * wreg[g][cc].y
                               + a.z * wreg[g][cc].z + a.w * wreg[g][cc].w;
                }
            }
        }

        // ---- (5) butterfly-reduce K-partials over the 16 ks lanes ----
        #pragma unroll
        for (int m = 1; m <= 8; m <<= 1)
            #pragma unroll
            for (int g = 0; g < 4; ++g)
                #pragma unroll
                for (int i = 0; i < 4; ++i)
                    acc[g][i] += __shfl_xor(acc[g][i], m, 64);

        // ---- (6) activations + publish (lanes ks<4: one (bl,col) each) ----
        if (ks < 4) {
            const int bl = blp + ks;
            float ig = sigm(acc[0][ks] + b4[0]);
            float fg = sigm(acc[1][ks] + b4[1]);
            float og = sigm(acc[2][ks] + b4[2]);
            float ch = tanhf(acc[3][ks] + b4[3]);
            c_state = fg * c_state + ig * ch;
            float hn = og * tanhf(c_state);
            astore64(&ringOwn[(t & 1) * 2048 + bl * 256 + col],
                     ((ull)__float_as_uint(hn) << 32) | (ull)(uint)(t + 1));
            if (layer == 1) {
                const int bglob = grp * 8 + bl;
                out[((size_t)bglob * TT + t) * HH + col] = hn;
                if (t == TT - 1) {
                    float* tail = out + (size_t)BB * TT * HH;
                    tail[bglob * HH + col] = hn;                // hT (last layer)
                    tail[BB * HH + bglob * HH + col] = c_state; // cT (last layer)
                }
            }
        }
        __syncthreads();  // protect inp/hrec before next iteration overwrites
    }
}

extern "C" void kernel_launch(void* const* d_in, const int* in_sizes, int n_in,
                              void* d_out, int out_size, void* d_ws, size_t ws_size,
                              hipStream_t stream) {
    (void)in_sizes; (void)n_in; (void)out_size; (void)ws_size;
    const float* x    = (const float*)d_in[0];
    const float* W    = (const float*)d_in[1];
    const float* bias = (const float*)d_in[2];
    float* out  = (float*)d_out;
    int*   sync = (int*)d_ws;
    ull*   ring = (ull*)((char*)d_ws + 4096);  // 8 communities x 32 KB = 256 KB

    hipMemsetAsync(d_ws, 0, 4096 + 8 * 4096 * sizeof(ull), stream);  // markers + ring tags
    hipLaunchKernelGGL(lstm_scan, dim3(128), dim3(NT), 0, stream, x, W, bias, out, ring, sync);
}

// Round 11
// 72035.468 us; speedup vs baseline: 1.0016x; 1.0016x over previous
//
#include <hip/hip_runtime.h>

#define BB 32
#define TT 2048
#define HH 256
#define NT 512

typedef unsigned long long ull;
typedef unsigned int uint;

__device__ __forceinline__ float sigm(float v) { return 1.0f / (1.0f + __expf(-v)); }

__device__ __forceinline__ int aload(const int* p) {
  return __hip_atomic_load(p, __ATOMIC_RELAXED, __HIP_MEMORY_SCOPE_AGENT);
}
__device__ __forceinline__ void astore(int* p, int v) {
  __hip_atomic_store(p, v, __ATOMIC_RELAXED, __HIP_MEMORY_SCOPE_AGENT);
}
__device__ __forceinline__ ull aload64(const ull* p) {
  return __hip_atomic_load(p, __ATOMIC_RELAXED, __HIP_MEMORY_SCOPE_AGENT);
}
__device__ __forceinline__ void astore64(ull* p, ull v) {
  __hip_atomic_store(p, v, __ATOMIC_RELAXED, __HIP_MEMORY_SCOPE_AGENT);
}

// Communities: c = layer*4 + grp (8 total, XCD-aligned via c = bid&7), 16 WGs each.
// ws: markers m[8][16] ints at +0; rings at +4096: per community 2 slots x 2048 pairs
//     {tag(lo32), hbits(hi32)}, pair idx = bl*256 + col. 32 KB/community (round-8 exact).
// Thread mapping: ks = tid&15 (K-slice, interleaved k = c*64+ks*4), blg = (tid>>4)&1
// (batch half), unit = tid>>5 (one hidden col). Tile: 4 gates x 4 batches, weights
// stationary in 128 VGPRs. ks-partials reduced by in-wave shfl_xor butterfly.
// NOTE: plain __launch_bounds__(NT) — round 10's (NT,2) capped VGPR at 128 and
// spilled wreg to scratch (127 GB HBM traffic). Grid = 128 WGs on 256 CUs, so
// 1 WG/CU regardless; let the allocator use up to 256 VGPRs.
__global__ __launch_bounds__(NT) void lstm_scan(
    const float* __restrict__ x,     // [B,T,H]
    const float* __restrict__ W,     // [L,4,H,2H]
    const float* __restrict__ bias,  // [L,4,H]
    float* __restrict__ out,         // [B,T,H] + hT[B,H] + cT[B,H]
    ull* __restrict__ ring,
    int* __restrict__ sync)
{
    const int bid   = blockIdx.x;
    const int c     = bid & 7;        // community == XCD slot
    const int ug    = bid >> 3;       // unit group 0..15
    const int layer = c >> 2;
    const int grp   = c & 3;          // batch group
    const int tid   = threadIdx.x;
    const int ks    = tid & 15;       // K-slice lane (wave bits 0-3)
    const int blg   = (tid >> 4) & 1; // batch half
    const int unit  = tid >> 5;       // 0..15
    const int col   = ug * 16 + unit;
    const int blp   = blg * 4;        // local batch base

    int* mOwn = sync + c * 16;
    int* mSib = sync + (4 + grp) * 16;             // layer-1 community, same grp
    ull* ringOwn = ring + (size_t)c * 4096;
    ull* ringIn  = ring + (size_t)grp * 4096;      // layer-0 community, same grp

    __shared__ float inp[8][268];
    __shared__ float hrec[8][268];

    // weight-stationary registers: wreg[gate][chunk] = W[l][gate][col][c*64 + ks*4 .. +3]
    float4 wreg[4][8];
    #pragma unroll
    for (int g = 0; g < 4; ++g)
        #pragma unroll
        for (int cc = 0; cc < 8; ++cc)
            wreg[g][cc] = *(const float4*)(
                W + (((size_t)layer * 4 + g) * HH + col) * (2 * HH) + cc * 64 + ks * 4);

    float b4[4];
    #pragma unroll
    for (int g = 0; g < 4; ++g) b4[g] = bias[((size_t)layer * 4 + g) * HH + col];

    const int prow = tid >> 6;          // staging row (local batch), round-8 map
    const int pcol = (tid & 63) << 2;   // staging col base

    float c_state = 0.f;  // valid on ks<4 lanes: (bl = blp+ks, col)

    for (int t = 0; t < TT; ++t) {
        // ---- (1) input stage: x (layer0) or h0 ring poll (layer1) ----
        if (layer == 0) {
            *(float4*)&inp[prow][pcol] =
                *(const float4*)(x + ((size_t)(grp * 8 + prow) * TT + t) * HH + pcol);
        } else {
            const ull* rin = ringIn + (t & 1) * 2048 + 4 * tid;  // h0(t), tag t+1
            const uint want = (uint)(t + 1);
            uint pend = 0xFu; ull v[4];
            for (;;) {
                #pragma unroll
                for (int j = 0; j < 4; ++j)
                    if (pend & (1u << j)) v[j] = aload64(&rin[j]);
                #pragma unroll
                for (int j = 0; j < 4; ++j)
                    if ((pend & (1u << j)) && (uint)v[j] == want) {
                        inp[prow][pcol + j] = __uint_as_float((uint)(v[j] >> 32));
                        pend &= ~(1u << j);
                    }
                if (!pend) break;
                __builtin_amdgcn_s_sleep(1);
            }
        }
        __syncthreads();  // inp ready

        // ---- (2) recurrent poll -> hrec (4 pairs/thread, round-8 exact) ----
        {
            const ull* rr_ = ringOwn + ((t + 1) & 1) * 2048 + 4 * tid;  // h_l(t-1), tag t
            const uint want = (uint)t;
            uint pend = 0xFu; ull v[4];
            for (;;) {
                #pragma unroll
                for (int j = 0; j < 4; ++j)
                    if (pend & (1u << j)) v[j] = aload64(&rr_[j]);
                #pragma unroll
                for (int j = 0; j < 4; ++j)
                    if ((pend & (1u << j)) && (uint)v[j] == want) {
                        hrec[prow][pcol + j] = __uint_as_float((uint)(v[j] >> 32));
                        pend &= ~(1u << j);
                    }
                if (!pend) break;
                __builtin_amdgcn_s_sleep(1);
            }
        }
        // ---- (3) WAR gates (round-8 exact; overlaps stragglers) ----
        if (tid < 16)                    { while (aload(&mOwn[tid]) < t)          __builtin_amdgcn_s_sleep(1); }
        else if (layer == 0 && tid < 32) { while (aload(&mSib[tid - 16]) < t - 1) __builtin_amdgcn_s_sleep(1); }
        __syncthreads();  // hrec ready + gates passed
        if (tid == 0) astore(&mOwn[ug], t + 1);  // staged step t (inp + hrec consumed)

        // ---- (4) dot: weights in regs, 4 a-reads feed 64 FMA per chunk ----
        float acc[4][4];
        #pragma unroll
        for (int g = 0; g < 4; ++g)
            #pragma unroll
            for (int i = 0; i < 4; ++i) acc[g][i] = 0.f;

        #pragma unroll
        for (int cc = 0; cc < 8; ++cc) {
            const int kof = cc * 64 + ks * 4;
            #pragma unroll
            for (int i = 0; i < 4; ++i) {
                float4 a = (cc < 4) ? *(const float4*)&inp[blp + i][kof]
                                    : *(const float4*)&hrec[blp + i][kof - 256];
                #pragma unroll
                for (int g = 0; g < 4; ++g) {
                    acc[g][i] += a.x * wreg[g][cc].x + a.y * wreg[g][cc].y
                               + a.z * wreg[g][cc].z + a.w * wreg[g][cc].w;
                }
            }
        }

        // ---- (5) butterfly-reduce K-partials over the 16 ks lanes ----
        #pragma unroll
        for (int m = 1; m <= 8; m <<= 1)
            #pragma unroll
            for (int g = 0; g < 4; ++g)
                #pragma unroll
                for (int i = 0; i < 4; ++i)
                    acc[g][i] += __shfl_xor(acc[g][i], m, 64);

        // ---- (6) activations + publish (lanes ks<4: one (bl,col) each) ----
        if (ks < 4) {
            const int bl = blp + ks;
            float ig = sigm(acc[0][ks] + b4[0]);
            float fg = sigm(acc[1][ks] + b4[1]);
            float og = sigm(acc[2][ks] + b4[2]);
            float ch = tanhf(acc[3][ks] + b4[3]);
            c_state = fg * c_state + ig * ch;
            float hn = og * tanhf(c_state);
            astore64(&ringOwn[(t & 1) * 2048 + bl * 256 + col],
                     ((ull)__float_as_uint(hn) << 32) | (ull)(uint)(t + 1));
            if (layer == 1) {
                const int bglob = grp * 8 + bl;
                out[((size_t)bglob * TT + t) * HH + col] = hn;
                if (t == TT - 1) {
                    float* tail = out + (size_t)BB * TT * HH;
                    tail[bglob * HH + col] = hn;                // hT (last layer)
                    tail[BB * HH + bglob * HH + col] = c_state; // cT (last layer)
                }
            }
        }
        __syncthreads();  // protect inp/hrec before next iteration overwrites
    }
}

extern "C" void kernel_launch(void* const* d_in, const int* in_sizes, int n_in,
                              void* d_out, int out_size, void* d_ws, size_t ws_size,
                              hipStream_t stream) {
    (void)in_sizes; (void)n_in; (void)out_size; (void)ws_size;
    const float* x    = (const float*)d_in[0];
    const float* W    = (const float*)d_in[1];
    const float* bias = (const float*)d_in[2];
    float* out  = (float*)d_out;
    int*   sync = (int*)d_ws;
    ull*   ring = (ull*)((char*)d_ws + 4096);  // 8 communities x 32 KB = 256 KB

    hipMemsetAsync(d_ws, 0, 4096 + 8 * 4096 * sizeof(ull), stream);  // markers + ring tags
    hipLaunchKernelGGL(lstm_scan, dim3(128), dim3(NT), 0, stream, x, W, bias, out, ring, sync);
}

// Round 12
// 7917.184 us; speedup vs baseline: 9.1135x; 9.0986x over previous
//
#include <hip/hip_runtime.h>

#define BB 32
#define TT 2048
#define HH 256
#define NT 512

typedef unsigned long long ull;
typedef unsigned int uint;

__device__ __forceinline__ float sigm(float v) { return 1.0f / (1.0f + __expf(-v)); }

__device__ __forceinline__ int aload(const int* p) {
  return __hip_atomic_load(p, __ATOMIC_RELAXED, __HIP_MEMORY_SCOPE_AGENT);
}
__device__ __forceinline__ void astore(int* p, int v) {
  __hip_atomic_store(p, v, __ATOMIC_RELAXED, __HIP_MEMORY_SCOPE_AGENT);
}
__device__ __forceinline__ ull aload64(const ull* p) {
  return __hip_atomic_load(p, __ATOMIC_RELAXED, __HIP_MEMORY_SCOPE_AGENT);
}
__device__ __forceinline__ void astore64(ull* p, ull v) {
  __hip_atomic_store(p, v, __ATOMIC_RELAXED, __HIP_MEMORY_SCOPE_AGENT);
}

// Communities: c = bid&7 (XCD-aligned) = layer*4 + grp; 32 WGs each (grid 256, all CUs).
// Each WG: 8 hidden cols (col = ug*8 + wave), 8 batches. Sync protocol = round-8 exact:
// per-community depth-2 tagged ring (2 slots x 2048 pairs {tag,hbits}, idx = bl*256+col)
// + 32 read-markers. Per-thread: 1 gate x 4 batches x K-slice 64 (interleaved k=j*32+ks*4),
// weights stationary in 16 float4 (64 VGPR) -> total ~115 VGPR, fits the 128 cap (r10/r11
// lesson: allocator caps at 128; spill = 127 GB HBM). Reduction: shfl butterfly over ks
// (xor 1,2,4) + gate gather (xor 8,16,24); static ternary picks (no runtime array idx).
__global__ __launch_bounds__(NT) void lstm_scan(
    const float* __restrict__ x,     // [B,T,H]
    const float* __restrict__ W,     // [L,4,H,2H]
    const float* __restrict__ bias,  // [L,4,H]
    float* __restrict__ out,         // [B,T,H] + hT[B,H] + cT[B,H]
    ull* __restrict__ ring,
    int* __restrict__ sync)
{
    const int bid   = blockIdx.x;
    const int c     = bid & 7;        // community == XCD slot
    const int ug    = bid >> 3;       // 0..31
    const int layer = c >> 2;
    const int grp   = c & 3;          // batch group
    const int tid   = threadIdx.x;
    const int lane  = tid & 63;
    const int wave  = tid >> 6;       // 0..7 -> col within group
    const int ks    = lane & 7;       // K-slice lane (bits 0-2)
    const int gate  = (lane >> 3) & 3;// bits 3-4: 0=i 1=f 2=o 3=chat
    const int bh    = lane >> 5;      // batch half (bit 5)
    const int col   = ug * 8 + wave;

    int* mOwn = sync + c * 32;
    int* mSib = sync + (4 + grp) * 32;             // layer-1 community, same grp
    ull* ringOwn = ring + (size_t)c * 4096;
    ull* ringIn  = ring + (size_t)grp * 4096;      // layer-0 community, same grp

    __shared__ float inp[8][268];
    __shared__ float hrec[8][268];

    // weight-stationary: wreg[j] = W[l][gate][col][j*32 + ks*4 .. +3], j=0..15 covers K=512/8ks
    float4 wreg[16];
    const float* Wrow = W + (((size_t)layer * 4 + gate) * HH + col) * (2 * HH);
    #pragma unroll
    for (int j = 0; j < 16; ++j) wreg[j] = *(const float4*)(Wrow + j * 32 + ks * 4);

    float bb[4];
    #pragma unroll
    for (int g = 0; g < 4; ++g) bb[g] = bias[((size_t)layer * 4 + g) * HH + col];

    const int prow = tid >> 6;          // staging row (local batch)
    const int pcol = (tid & 63) << 2;   // staging col base

    float c_state = 0.f;  // valid on publish lanes (gate==0 && ks<4): (bl=bh*4+ks, col)

    for (int t = 0; t < TT; ++t) {
        // ---- (1) input stage: x (layer0) or h0 ring poll (layer1) ----
        if (layer == 0) {
            *(float4*)&inp[prow][pcol] =
                *(const float4*)(x + ((size_t)(grp * 8 + prow) * TT + t) * HH + pcol);
        } else {
            const ull* rin = ringIn + (t & 1) * 2048 + 4 * tid;  // h0(t), tag t+1
            const uint want = (uint)(t + 1);
            uint pend = 0xFu; ull v[4];
            for (;;) {
                #pragma unroll
                for (int j = 0; j < 4; ++j)
                    if (pend & (1u << j)) v[j] = aload64(&rin[j]);
                #pragma unroll
                for (int j = 0; j < 4; ++j)
                    if ((pend & (1u << j)) && (uint)v[j] == want) {
                        inp[prow][pcol + j] = __uint_as_float((uint)(v[j] >> 32));
                        pend &= ~(1u << j);
                    }
                if (!pend) break;
                __builtin_amdgcn_s_sleep(1);
            }
        }
        __syncthreads();  // inp ready

        // ---- (2) recurrent poll -> hrec (4 pairs/thread, round-8 exact) ----
        {
            const ull* rr_ = ringOwn + ((t + 1) & 1) * 2048 + 4 * tid;  // h_l(t-1), tag t
            const uint want = (uint)t;
            uint pend = 0xFu; ull v[4];
            for (;;) {
                #pragma unroll
                for (int j = 0; j < 4; ++j)
                    if (pend & (1u << j)) v[j] = aload64(&rr_[j]);
                #pragma unroll
                for (int j = 0; j < 4; ++j)
                    if ((pend & (1u << j)) && (uint)v[j] == want) {
                        hrec[prow][pcol + j] = __uint_as_float((uint)(v[j] >> 32));
                        pend &= ~(1u << j);
                    }
                if (!pend) break;
                __builtin_amdgcn_s_sleep(1);
            }
        }
        // ---- (3) WAR gates (round-8 exact; overlaps stragglers) ----
        if (tid < 32)                    { while (aload(&mOwn[tid]) < t)          __builtin_amdgcn_s_sleep(1); }
        else if (layer == 0 && tid < 64) { while (aload(&mSib[tid - 32]) < t - 1) __builtin_amdgcn_s_sleep(1); }
        __syncthreads();  // hrec ready + gates passed
        if (tid == 0) astore(&mOwn[ug], t + 1);  // staged step t (inp + hrec consumed)

        // ---- (4) dot: weights in regs; 4 batches x K-slice 64, interleaved k ----
        float a0 = 0.f, a1 = 0.f, a2 = 0.f, a3 = 0.f;
        const int rb = bh * 4;
        #pragma unroll
        for (int j = 0; j < 8; ++j) {
            const int kof = j * 32 + ks * 4;
            float4 w = wreg[j];
            float4 v0 = *(const float4*)&inp[rb + 0][kof];
            float4 v1 = *(const float4*)&inp[rb + 1][kof];
            float4 v2 = *(const float4*)&inp[rb + 2][kof];
            float4 v3 = *(const float4*)&inp[rb + 3][kof];
            a0 += v0.x * w.x + v0.y * w.y + v0.z * w.z + v0.w * w.w;
            a1 += v1.x * w.x + v1.y * w.y + v1.z * w.z + v1.w * w.w;
            a2 += v2.x * w.x + v2.y * w.y + v2.z * w.z + v2.w * w.w;
            a3 += v3.x * w.x + v3.y * w.y + v3.z * w.z + v3.w * w.w;
        }
        #pragma unroll
        for (int j = 8; j < 16; ++j) {
            const int kof = (j - 8) * 32 + ks * 4;
            float4 w = wreg[j];
            float4 v0 = *(const float4*)&hrec[rb + 0][kof];
            float4 v1 = *(const float4*)&hrec[rb + 1][kof];
            float4 v2 = *(const float4*)&hrec[rb + 2][kof];
            float4 v3 = *(const float4*)&hrec[rb + 3][kof];
            a0 += v0.x * w.x + v0.y * w.y + v0.z * w.z + v0.w * w.w;
            a1 += v1.x * w.x + v1.y * w.y + v1.z * w.z + v1.w * w.w;
            a2 += v2.x * w.x + v2.y * w.y + v2.z * w.z + v2.w * w.w;
            a3 += v3.x * w.x + v3.y * w.y + v3.z * w.z + v3.w * w.w;
        }

        // ---- (5) butterfly over ks lanes (xor 1,2,4) ----
        #pragma unroll
        for (int m = 1; m <= 4; m <<= 1) {
            a0 += __shfl_xor(a0, m);
            a1 += __shfl_xor(a1, m);
            a2 += __shfl_xor(a2, m);
            a3 += __shfl_xor(a3, m);
        }
        // ---- gate gather (xor 8,16,24): on gate==0 lanes, f/o/q from gates 1/2/3 ----
        float f0 = __shfl_xor(a0, 8),  f1 = __shfl_xor(a1, 8),  f2 = __shfl_xor(a2, 8),  f3 = __shfl_xor(a3, 8);
        float o0 = __shfl_xor(a0, 16), o1 = __shfl_xor(a1, 16), o2 = __shfl_xor(a2, 16), o3 = __shfl_xor(a3, 16);
        float q0 = __shfl_xor(a0, 24), q1 = __shfl_xor(a1, 24), q2 = __shfl_xor(a2, 24), q3 = __shfl_xor(a3, 24);

        // ---- (6) activations + publish (lanes gate==0 && ks<4: bl = bh*4+ks) ----
        if (gate == 0 && ks < 4) {
            const int bl = rb + ks;
            float av = ks == 0 ? a0 : ks == 1 ? a1 : ks == 2 ? a2 : a3;
            float fv = ks == 0 ? f0 : ks == 1 ? f1 : ks == 2 ? f2 : f3;
            float ov = ks == 0 ? o0 : ks == 1 ? o1 : ks == 2 ? o2 : o3;
            float qv = ks == 0 ? q0 : ks == 1 ? q1 : ks == 2 ? q2 : q3;
            float ig = sigm(av + bb[0]);
            float fg = sigm(fv + bb[1]);
            float og = sigm(ov + bb[2]);
            float ch = tanhf(qv + bb[3]);
            c_state = fg * c_state + ig * ch;
            float hn = og * tanhf(c_state);
            astore64(&ringOwn[(t & 1) * 2048 + bl * 256 + col],
                     ((ull)__float_as_uint(hn) << 32) | (ull)(uint)(t + 1));
            if (layer == 1) {
                const int bglob = grp * 8 + bl;
                out[((size_t)bglob * TT + t) * HH + col] = hn;
                if (t == TT - 1) {
                    float* tail = out + (size_t)BB * TT * HH;
                    tail[bglob * HH + col] = hn;                // hT (last layer)
                    tail[BB * HH + bglob * HH + col] = c_state; // cT (last layer)
                }
            }
        }
        __syncthreads();  // protect inp/hrec before next iteration overwrites
    }
}

extern "C" void kernel_launch(void* const* d_in, const int* in_sizes, int n_in,
                              void* d_out, int out_size, void* d_ws, size_t ws_size,
                              hipStream_t stream) {
    (void)in_sizes; (void)n_in; (void)out_size; (void)ws_size;
    const float* x    = (const float*)d_in[0];
    const float* W    = (const float*)d_in[1];
    const float* bias = (const float*)d_in[2];
    float* out  = (float*)d_out;
    int*   sync = (int*)d_ws;
    ull*   ring = (ull*)((char*)d_ws + 4096);  // 8 communities x 32 KB = 256 KB

    hipMemsetAsync(d_ws, 0, 4096 + 8 * 4096 * sizeof(ull), stream);  // markers + ring tags
    hipLaunchKernelGGL(lstm_scan, dim3(256), dim3(NT), 0, stream, x, W, bias, out, ring, sync);
}